// Round 1
// baseline (348.119 us; speedup 1.0000x reference)
//
#include <hip/hip_runtime.h>
#include <stdint.h>

#define T_STEPS 30
#define HDIM 32
#define BTOT 65536

typedef __bf16 bf16_t;
typedef bf16_t bf16x8 __attribute__((ext_vector_type(8)));
typedef float f32x4 __attribute__((ext_vector_type(4)));

__device__ __forceinline__ float fast_sigmoid(float x) {
    return __builtin_amdgcn_rcpf(1.0f + __expf(-x));
}
__device__ __forceinline__ float fast_tanh(float x) {
    // tanh(x) = 2*sigmoid(2x) - 1 ; graceful at extremes (rcp(inf)=0 -> -1)
    return 2.0f * __builtin_amdgcn_rcpf(1.0f + __expf(-2.0f * x)) - 1.0f;
}

// One LSTM cell step for 16 batch rows handled by one wave.
// MFMA 16x16x32 bf16:
//   A (16 batch x 32 k):   lane holds row = lane&15, k = (lane>>4)*8 + j (j=0..7)
//   B (32 k x 128 gates):  stored pre-swizzled in LDS, 1 ds_read_b128 per 16-col tile
//   C/D (16 batch x 16 n): col = lane&15, row = (lane>>4)*4 + reg   [verified m89/m91]
// Gate tiles: 0,1 = i ; 2,3 = f ; 4,5 = g ; 6,7 = o  (PyTorch order)
template <int LI, bool SAVE>
__device__ __forceinline__ void cell(
    int lane, int lrow, int kgrp,
    const bf16_t* __restrict__ wb,       // laundered LDS weight-fragment base
    const float (&breg)[3][8],
    bf16x8 ain,                          // input A-fragment (x or h from layer below)
    bf16x8& ah,                          // in: h_{t-1} A-frag ; out: h_t A-frag
    float (&cst)[3][2][4],               // fp32 cell state
    float (&hsave)[2][4],                // fp32 h of last layer (for the head)
    bf16_t (*hb)[32])                    // this wave's private h exchange buffer
{
    constexpr int WIH_OFF = ((LI == 0) ? 0 : (LI == 1) ? 2 : 4) * 4096;
    constexpr int WHH_OFF = WIH_OFF + 4096;

    f32x4 acc[8];
#pragma unroll
    for (int tl = 0; tl < 8; ++tl) {
        const float bb = breg[LI][tl];
        acc[tl][0] = bb; acc[tl][1] = bb; acc[tl][2] = bb; acc[tl][3] = bb;
    }
#pragma unroll
    for (int tl = 0; tl < 8; ++tl) {
        bf16x8 bfr = *(const bf16x8*)(wb + WIH_OFF + (tl << 9) + (lane << 3));
        acc[tl] = __builtin_amdgcn_mfma_f32_16x16x32_bf16(ain, bfr, acc[tl], 0, 0, 0);
    }
#pragma unroll
    for (int tl = 0; tl < 8; ++tl) {
        bf16x8 bfr = *(const bf16x8*)(wb + WHH_OFF + (tl << 9) + (lane << 3));
        acc[tl] = __builtin_amdgcn_mfma_f32_16x16x32_bf16(ah, bfr, acc[tl], 0, 0, 0);
    }
    // activations + state update, fp32
#pragma unroll
    for (int mt = 0; mt < 2; ++mt) {
#pragma unroll
        for (int r = 0; r < 4; ++r) {
            const float iv = fast_sigmoid(acc[0 + mt][r]);
            const float fv = fast_sigmoid(acc[2 + mt][r]);
            const float gv = fast_tanh(acc[4 + mt][r]);
            const float ov = fast_sigmoid(acc[6 + mt][r]);
            const float cc = fv * cst[LI][mt][r] + iv * gv;
            cst[LI][mt][r] = cc;
            const float hv = ov * fast_tanh(cc);
            if (SAVE) hsave[mt][r] = hv;
            hb[kgrp * 4 + r][mt * 16 + lrow] = (bf16_t)hv;  // C-layout -> [batch][m]
        }
    }
    // reload h_t as an A-fragment (intra-wave LDS, in-order DS pipe: no barrier)
    ah = *(const bf16x8*)(&hb[lrow][kgrp << 3]);
}

__global__ __launch_bounds__(256, 2) void lstm3_fused(
    const float* __restrict__ X,
    const float* __restrict__ Wih0, const float* __restrict__ Whh0,
    const float* __restrict__ bih0, const float* __restrict__ bhh0,
    const float* __restrict__ Wih1, const float* __restrict__ Whh1,
    const float* __restrict__ bih1, const float* __restrict__ bhh1,
    const float* __restrict__ Wih2, const float* __restrict__ Whh2,
    const float* __restrict__ bih2, const float* __restrict__ bhh2,
    const float* __restrict__ W1, const float* __restrict__ b1,
    const float* __restrict__ W2, const float* __restrict__ b2,
    float* __restrict__ out)
{
    // LDS: 6 weight matrices as pre-swizzled bf16 B-fragments (48 KB)
    //      + combined bias (1.5 KB) + per-wave h exchange (4 KB) + final h fp32 (8 KB)
    __shared__ alignas(16) bf16_t wfrag[6 * 4096];
    __shared__ float bias_s[3][128];
    __shared__ alignas(16) bf16_t hbuf[4][16][32];
    __shared__ alignas(16) float hfin[4][16][32];

    const int tid = threadIdx.x;

    // ---- stage: wfrag[mat][tile*512 + lane*8 + j] = B[k][n] = W[n][k] (bf16) ----
    auto stage = [&](int mat, const float* __restrict__ w, int K) {
        for (int p = tid; p < 4096; p += 256) {
            const int tile = p >> 9;
            const int r = p & 511;
            const int ln = r >> 3;
            const int j = r & 7;
            const int k = ((ln >> 4) << 3) + j;        // k = (lane>>4)*8 + j
            const int n = (tile << 4) + (ln & 15);     // n = tile*16 + (lane&15)
            const float v = (k < K) ? w[n * K + k] : 0.0f;
            wfrag[mat * 4096 + p] = (bf16_t)v;
        }
    };
    stage(0, Wih0, 3);
    stage(1, Whh0, HDIM);
    stage(2, Wih1, HDIM);
    stage(3, Whh1, HDIM);
    stage(4, Wih2, HDIM);
    stage(5, Whh2, HDIM);
    for (int p = tid; p < 384; p += 256) {
        const int l = p >> 7, n = p & 127;
        float v;
        if (l == 0)      v = bih0[n] + bhh0[n];
        else if (l == 1) v = bih1[n] + bhh1[n];
        else             v = bih2[n] + bhh2[n];
        bias_s[l][n] = v;
    }
    __syncthreads();

    const int wave = tid >> 6;
    const int lane = tid & 63;
    const int lrow = lane & 15;   // batch row within wave tile / C col
    const int kgrp = lane >> 4;   // k-group / C row-group
    const int b0 = blockIdx.x * 64 + wave * 16;

    // biases -> registers (col-indexed, loop-invariant)
    float breg[3][8];
#pragma unroll
    for (int l = 0; l < 3; ++l)
#pragma unroll
        for (int tl = 0; tl < 8; ++tl)
            breg[l][tl] = bias_s[l][tl * 16 + lrow];

    float cst[3][2][4];
#pragma unroll
    for (int l = 0; l < 3; ++l)
#pragma unroll
        for (int mt = 0; mt < 2; ++mt)
#pragma unroll
            for (int r = 0; r < 4; ++r) cst[l][mt][r] = 0.0f;

    bf16x8 ah0, ah1, ah2;
#pragma unroll
    for (int j = 0; j < 8; ++j) { ah0[j] = (bf16_t)0.0f; ah1[j] = (bf16_t)0.0f; ah2[j] = (bf16_t)0.0f; }
    float h2keep[2][4];
#pragma unroll
    for (int mt = 0; mt < 2; ++mt)
#pragma unroll
        for (int r = 0; r < 4; ++r) h2keep[mt][r] = 0.0f;

    bf16_t (*hb)[32] = hbuf[wave];

    // x stream (lane lrow's batch row); lanes 16..63 duplicate-load (L1 broadcast)
    const float* xlane = X + (size_t)(b0 + lrow) * (T_STEPS * 3);
    float cx0 = xlane[0], cx1 = xlane[1], cx2 = xlane[2];

    for (int t = 0; t < T_STEPS; ++t) {
        // prefetch next step's x under this step's compute
        const int tn = (t < T_STEPS - 1) ? (t + 1) : (T_STEPS - 1);
        const float nx0 = xlane[tn * 3 + 0];
        const float nx1 = xlane[tn * 3 + 1];
        const float nx2 = xlane[tn * 3 + 2];

        // launder LDS base each iteration: blocks LICM from hoisting 48 weight
        // fragments (192 VGPRs!) out of the loop
        unsigned lz = 0;
        asm volatile("" : "+v"(lz));
        const bf16_t* wbt = wfrag + lz;

        // x A-fragment: only k-group 0 holds k=0..2
        bf16x8 ax;
#pragma unroll
        for (int j = 0; j < 8; ++j) ax[j] = (bf16_t)0.0f;
        if (kgrp == 0) { ax[0] = (bf16_t)cx0; ax[1] = (bf16_t)cx1; ax[2] = (bf16_t)cx2; }

        cell<0, false>(lane, lrow, kgrp, wbt, breg, ax,  ah0, cst, h2keep, hb);
        cell<1, false>(lane, lrow, kgrp, wbt, breg, ah0, ah1, cst, h2keep, hb);
        cell<2, true >(lane, lrow, kgrp, wbt, breg, ah1, ah2, cst, h2keep, hb);

        cx0 = nx0; cx1 = nx1; cx2 = nx2;
    }

    // ---- head: out = (h2 @ W1^T + b1) @ W2^T + b2, fp32 ----
#pragma unroll
    for (int mt = 0; mt < 2; ++mt)
#pragma unroll
        for (int r = 0; r < 4; ++r)
            hfin[wave][kgrp * 4 + r][mt * 16 + lrow] = h2keep[mt][r];

    if (lane < 16) {
        float hv[HDIM];
#pragma unroll
        for (int k = 0; k < HDIM; ++k) hv[k] = hfin[wave][lane][k];
        float y1[16];
#pragma unroll
        for (int o = 0; o < 16; ++o) {
            float a = b1[o];
#pragma unroll
            for (int k = 0; k < HDIM; ++k) a += hv[k] * W1[o * 32 + k];
            y1[o] = a;
        }
        const int b = b0 + lane;
#pragma unroll
        for (int q = 0; q < 7; ++q) {
            float a = b2[q];
#pragma unroll
            for (int o = 0; o < 16; ++o) a += y1[o] * W2[q * 16 + o];
            out[b * 7 + q] = a;
        }
    }
}

extern "C" void kernel_launch(void* const* d_in, const int* in_sizes, int n_in,
                              void* d_out, int out_size, void* d_ws, size_t ws_size,
                              hipStream_t stream) {
    (void)in_sizes; (void)n_in; (void)d_ws; (void)ws_size; (void)out_size;
    const float* X    = (const float*)d_in[0];
    const float* Wih0 = (const float*)d_in[1];
    const float* Whh0 = (const float*)d_in[2];
    const float* bih0 = (const float*)d_in[3];
    const float* bhh0 = (const float*)d_in[4];
    const float* Wih1 = (const float*)d_in[5];
    const float* Whh1 = (const float*)d_in[6];
    const float* bih1 = (const float*)d_in[7];
    const float* bhh1 = (const float*)d_in[8];
    const float* Wih2 = (const float*)d_in[9];
    const float* Whh2 = (const float*)d_in[10];
    const float* bih2 = (const float*)d_in[11];
    const float* bhh2 = (const float*)d_in[12];
    const float* W1   = (const float*)d_in[13];
    const float* b1   = (const float*)d_in[14];
    const float* W2   = (const float*)d_in[15];
    const float* b2   = (const float*)d_in[16];
    float* out = (float*)d_out;

    dim3 grid(BTOT / 64), block(256);
    hipLaunchKernelGGL(lstm3_fused, grid, block, 0, stream,
                       X, Wih0, Whh0, bih0, bhh0, Wih1, Whh1, bih1, bhh1,
                       Wih2, Whh2, bih2, bhh2, W1, b1, W2, b2, out);
}